// Round 1
// baseline (224.673 us; speedup 1.0000x reference)
//
#include <hip/hip_runtime.h>
#include <hip/hip_bf16.h>

// B=512, T=2048, S=16, H=128, A=4.  NTOK = 1,048,576 tokens.
// Transposed MFMA chain, v_mfma_f32_16x16x16f16 (K=16: D layout == B layout,
// so chained GEMMs need no data movement; tokens live in lanes).
// Numerics (verified rounds 6/8/9, absmax 0.0625): QP-amplified chain
// (z2/sech2/dh/f/G) in split-f16 (hi+lo, 3 MFMAs/product); u_unc chain
// (z1->ua) single f16 (O(1) sensitivity).  This round does NOT change the
// numerics path except a <=1ulp exp2 constant fold in fast_tanh.
// Round-10 structure (this file): r9 LDS-weight layout + in-block pack,
// PLUS (a) 2-tile batching per loop iter: A-frag/bias LDS reads shared
// between two token tiles, doubles independent MFMA/tanh chains to fill
// the 28% VALU-idle seen in r9 counters (VALUBusy 72 / Mfma 26 / Occ 38);
// (b) next-pair state prefetch (hides ~500-900cy global latency/tile);
// (c) fast_tanh via exp2(x*2log2e): 1 mul instead of 2 per eval;
// (d) bg bias quads re-read in epilogue (broadcast LDS) not held in regs.
// Spill tripwire: VGPR_Count must stay <128 and hbm_bytes ~50MB.
#define HDIM 128
#define SDIM 16
#define ADIM 4
#define NTOK (512 * 2048)
#define NTILE (NTOK / 16)      // 65536 16-token tiles
#define NBLK 2048
#define WPB 4                  // waves per 256-thread block
#define TPW (NTILE / (NBLK * WPB))   // 8 tiles per wave (4 pairs)

typedef _Float16 half4 __attribute__((ext_vector_type(4)));
typedef float f32x4 __attribute__((ext_vector_type(4)));

__device__ __forceinline__ f32x4 mm(half4 a, half4 b, f32x4 c) {
    return __builtin_amdgcn_mfma_f32_16x16x16f16(a, b, c, 0, 0, 0);
}
__device__ __forceinline__ float fast_tanh(float x) {
    // e^{2x} = 2^{x * 2log2(e)}; 1 mul + v_exp + add + rcp + fma
    float e = __builtin_amdgcn_exp2f(x * 2.88539008177792681f);
    return 1.0f - 2.0f * __builtin_amdgcn_rcpf(e + 1.0f);
}
__device__ __forceinline__ f32x4 tanh4(f32x4 z) {
    f32x4 r;
    r.x = fast_tanh(z.x); r.y = fast_tanh(z.y);
    r.z = fast_tanh(z.z); r.w = fast_tanh(z.w);
    return r;
}
__device__ __forceinline__ half4 toh(f32x4 v) {
    half4 h;
    h.x = (_Float16)v.x; h.y = (_Float16)v.y;
    h.z = (_Float16)v.z; h.w = (_Float16)v.w;
    return h;
}
// split fp32 vector into f16 hi + f16 lo (x ~= hi + lo, residual ~2^-22 x)
// UNCHANGED from verified r9 (RTN path) — do not touch without re-verifying.
__device__ __forceinline__ void split4(f32x4 v, half4& hi, half4& lo) {
    hi = toh(v);
    f32x4 r;
    r.x = v.x - (float)hi.x; r.y = v.y - (float)hi.y;
    r.z = v.z - (float)hi.z; r.w = v.w - (float)hi.w;
    lo = toh(r);
}
__device__ __forceinline__ float dot4(f32x4 a, f32x4 b) {
    return a.x*b.x + a.y*b.y + a.z*b.z + a.w*b.w;
}
__device__ __forceinline__ float redq(float v) {   // sum over the 4 lane-quads
    v += __shfl_xor(v, 16, 64);
    v += __shfl_xor(v, 32, 64);
    return v;
}

__global__ __launch_bounds__(256, 4) void cbf_qp_kernel(
    const float* __restrict__ state,
    const float* __restrict__ Wc1, const float* __restrict__ bc1,
    const float* __restrict__ Wc2, const float* __restrict__ bc2,
    const float* __restrict__ Wh1, const float* __restrict__ bh1,
    const float* __restrict__ wh2, const float* __restrict__ bh2,
    const float* __restrict__ Wf,  const float* __restrict__ bf,
    const float* __restrict__ Wg,  const float* __restrict__ bg,
    float* __restrict__ out)
{
    // ---- LDS weight A-frags: [chunk][lane] half4 --------------------------
    __shared__ __align__(16) half4 az1_s[8 * 64];    // Wc1^T
    __shared__ __align__(16) half4 aua_s[8 * 64];    // Wc2^T (rows >= 4 zero)
    __shared__ __align__(16) half4 az2h_s[8 * 64];   // Wh1^T hi
    __shared__ __align__(16) half4 az2l_s[8 * 64];   // Wh1^T lo
    __shared__ __align__(16) half4 adhh_s[8 * 64];   // (Wh1 .* wh2) hi
    __shared__ __align__(16) half4 adhl_s[8 * 64];   // (Wh1 .* wh2) lo
    __shared__ __align__(16) half4 afh_s[64];        // Wf^T hi
    __shared__ __align__(16) half4 afl_s[64];        // Wf^T lo
    __shared__ __align__(16) half4 agh_s[4 * 64];    // Wg^T permuted hi (chunk a: A[s][k]=Wg[k][s*4+a])
    __shared__ __align__(16) half4 agl_s[4 * 64];    // Wg^T permuted lo
    __shared__ __align__(16) float bgt_s[64];        // bgt[a][s] = bg[s*4+a]
    __shared__ __align__(16) float bc1_s[HDIM];      // biases staged to LDS so the
    __shared__ __align__(16) float bh1_s[HDIM];      // allocator can't hoist 96 regs
    __shared__ __align__(16) float wh2_s[HDIM];      // of loop-invariant loads (r6)

    const int tid = threadIdx.x;

    // ---- per-block pack: raw global weights -> LDS frags ------------------
    // A-frag layout: lane l holds A[m][k], m = l&15, k = (l>>4)*4 + e
    for (int idx = tid; idx < 8 * 64; idx += 256) {
        const int c = idx >> 6, lane = idx & 63;
        const int m = lane & 15, q = lane >> 4;
        half4 hz1, hua, h2h, h2l, hdh, hdl;
        #pragma unroll
        for (int e = 0; e < 4; ++e) {
            const int k = q * 4 + e;
            const int j = c * 16 + k;
            hz1[e] = (_Float16)Wc1[k * HDIM + c*16 + m];
            hua[e] = (m < ADIM) ? (_Float16)Wc2[j * ADIM + m] : (_Float16)0.f;
            float w2 = Wh1[k * HDIM + c*16 + m];
            _Float16 hh = (_Float16)w2;
            h2h[e] = hh; h2l[e] = (_Float16)(w2 - (float)hh);
            float wd = Wh1[m * HDIM + j] * wh2[j];
            _Float16 hd = (_Float16)wd;
            hdh[e] = hd; hdl[e] = (_Float16)(wd - (float)hd);
        }
        az1_s[idx] = hz1;  aua_s[idx] = hua;
        az2h_s[idx] = h2h; az2l_s[idx] = h2l;
        adhh_s[idx] = hdh; adhl_s[idx] = hdl;
    }
    if (tid < 64) {                                  // Wf^T split
        const int m = tid & 15, q = tid >> 4;
        half4 fh, fl;
        #pragma unroll
        for (int e = 0; e < 4; ++e) {
            float w = Wf[(q*4+e) * SDIM + m];
            _Float16 h = (_Float16)w;
            fh[e] = h; fl[e] = (_Float16)(w - (float)h);
        }
        afh_s[tid] = fh; afl_s[tid] = fl;
    }
    {                                                // Wg^T row-permuted split
        const int a = tid >> 6, lane = tid & 63;
        const int m = lane & 15, q = lane >> 4;      // m = s index
        half4 gh, gl;
        #pragma unroll
        for (int e = 0; e < 4; ++e) {
            float w = Wg[(q*4+e) * 64 + m*4 + a];
            _Float16 h = (_Float16)w;
            gh[e] = h; gl[e] = (_Float16)(w - (float)h);
        }
        agh_s[tid] = gh; agl_s[tid] = gl;
    }
    if (tid < 64)                                    // bgt[a][s] = bg[s*4+a]
        bgt_s[(tid >> 4) * 16 + (tid & 15)] = bg[(tid & 15) * 4 + (tid >> 4)];
    if (tid < HDIM) {
        bc1_s[tid] = bc1[tid];
        bh1_s[tid] = bh1[tid];
        wh2_s[tid] = wh2[tid];
    }
    __syncthreads();

    // ---- main: 4 pairs of 16-token tiles per wave -------------------------
    const int lane = tid & 63;
    const int q = lane >> 4, n = lane & 15;
    const int wid = blockIdx.x * WPB + (tid >> 6);
    const int base = wid * TPW;

    f32x4 bfC = *(const f32x4*)(bf + q*4);
    f32x4 uaC;
    {
        f32x4 b2 = *(const f32x4*)(bc2);
        uaC.x = q == 0 ? b2.x : 0.f; uaC.y = q == 0 ? b2.y : 0.f;
        uaC.z = q == 0 ? b2.z : 0.f; uaC.w = q == 0 ? b2.w : 0.f;
    }
    const float bh2v = bh2[0];

    // prime the prefetch pipeline: pair 0
    f32x4 sv0 = *(const f32x4*)(state + (size_t)((base + 0)*16 + n) * SDIM + q*4);
    f32x4 sv1 = *(const f32x4*)(state + (size_t)((base + 1)*16 + n) * SDIM + q*4);

    for (int p = 0; p < TPW/2; ++p) {
        const int t0 = base + 2*p;
        // prefetch next pair (clamped: last iter re-reads same lines, L1-hit)
        const int np = (p + 1 < TPW/2) ? (p + 1) : p;
        f32x4 nsv0 = *(const f32x4*)(state + (size_t)((base + 2*np    )*16 + n) * SDIM + q*4);
        f32x4 nsv1 = *(const f32x4*)(state + (size_t)((base + 2*np + 1)*16 + n) * SDIM + q*4);

        half4 bsh0, bsl0, bsh1, bsl1;
        split4(sv0, bsh0, bsl0);
        split4(sv1, bsh1, bsl1);

        // Split accumulators (r8): dh 3x 8-deep chains, ua 2x, hp 2x — per tile.
        f32x4 ua0A = uaC, ua0B = {0.f, 0.f, 0.f, 0.f};
        f32x4 ua1A = uaC, ua1B = {0.f, 0.f, 0.f, 0.f};
        f32x4 dh0A = {0.f,0.f,0.f,0.f}, dh0B = {0.f,0.f,0.f,0.f}, dh0C = {0.f,0.f,0.f,0.f};
        f32x4 dh1A = {0.f,0.f,0.f,0.f}, dh1B = {0.f,0.f,0.f,0.f}, dh1C = {0.f,0.f,0.f,0.f};
        float hp0a = 0.f, hp0b = 0.f, hp1a = 0.f, hp1b = 0.f;

        #pragma unroll 2
        for (int c = 0; c < 8; ++c) {
            // ---- low-precision chain: z1 -> tanh -> ua (O(1) sensitivity)
            // A-frags/biases read ONCE, shared by both tiles of the pair.
            f32x4 b1 = *(const f32x4*)(&bc1_s[c*16 + q*4]);
            half4 a1 = az1_s[c*64 + lane];
            f32x4 z10 = mm(a1, bsh0, b1);
            f32x4 z11 = mm(a1, bsh1, b1);
            half4 t1h0 = toh(tanh4(z10));
            half4 t1h1 = toh(tanh4(z11));
            half4 au = aua_s[c*64 + lane];
            if (c & 1) { ua0B = mm(au, t1h0, ua0B); ua1B = mm(au, t1h1, ua1B); }
            else       { ua0A = mm(au, t1h0, ua0A); ua1A = mm(au, t1h1, ua1A); }

            // ---- high-precision chain: z2 (split x split, 3 MFMAs each)
            f32x4 b2v = *(const f32x4*)(&bh1_s[c*16 + q*4]);
            half4 a2h = az2h_s[c*64 + lane];
            half4 a2l = az2l_s[c*64 + lane];
            f32x4 z20 = mm(a2h, bsl0, b2v);
            z20 = mm(a2l, bsh0, z20);
            z20 = mm(a2h, bsh0, z20);
            f32x4 z21 = mm(a2h, bsl1, b2v);
            z21 = mm(a2l, bsh1, z21);
            z21 = mm(a2h, bsh1, z21);
            f32x4 t20 = tanh4(z20);
            f32x4 t21 = tanh4(z21);
            f32x4 s20, s21;
            s20.x = 1.f - t20.x*t20.x; s20.y = 1.f - t20.y*t20.y;
            s20.z = 1.f - t20.z*t20.z; s20.w = 1.f - t20.w*t20.w;
            s21.x = 1.f - t21.x*t21.x; s21.y = 1.f - t21.y*t21.y;
            s21.z = 1.f - t21.z*t21.z; s21.w = 1.f - t21.w*t21.w;
            half4 s2h0, s2l0, s2h1, s2l1;
            split4(s20, s2h0, s2l0);
            split4(s21, s2h1, s2l1);
            half4 adh = adhh_s[c*64 + lane];
            half4 adl = adhl_s[c*64 + lane];
            dh0A = mm(adh, s2h0, dh0A);
            dh0B = mm(adl, s2h0, dh0B);
            dh0C = mm(adh, s2l0, dh0C);
            dh1A = mm(adh, s2h1, dh1A);
            dh1B = mm(adl, s2h1, dh1B);
            dh1C = mm(adh, s2l1, dh1C);

            f32x4 wv = *(const f32x4*)(&wh2_s[c*16 + q*4]);
            if (c & 1) { hp0b += dot4(wv, t20); hp1b += dot4(wv, t21); }
            else       { hp0a += dot4(wv, t20); hp1a += dot4(wv, t21); }
        }
        f32x4 ua0 = ua0A + ua0B;
        f32x4 ua1 = ua1A + ua1B;
        f32x4 dh0 = dh0A + dh0B + dh0C;
        f32x4 dh1 = dh1A + dh1B + dh1C;
        float hpp0 = hp0a + hp0b;
        float hpp1 = hp1a + hp1b;

        // f^T (rows = s) — split path, frags shared by the pair
        half4 fh = afh_s[lane], fl = afl_s[lane];
        f32x4 fD0 = mm(fh, bsl0, bfC); fD0 = mm(fl, bsh0, fD0); fD0 = mm(fh, bsh0, fD0);
        f32x4 fD1 = mm(fh, bsl1, bfC); fD1 = mm(fl, bsh1, fD1); fD1 = mm(fh, bsh1, fD1);

        // right = h + bh2 + dh.f   (partials live in lane-quads; reduce)
        float right0 = redq(hpp0 + dot4(dh0, fD0)) + bh2v;
        float right1 = redq(hpp1 + dot4(dh1, fD1)) + bh2v;

        // G chunks (chunk a: row s = g[s][a]); compute + reduce per a so the
        // G registers stay transient (VGPR discipline for the batched body)
        float l00, l01, l02, l03, l10, l11, l12, l13;
        {
            half4 gh = agh_s[0*64 + lane], gl = agl_s[0*64 + lane];
            f32x4 bgC = *(const f32x4*)(&bgt_s[0*16 + q*4]);
            f32x4 Ga = mm(gh, bsl0, bgC); Ga = mm(gl, bsh0, Ga); Ga = mm(gh, bsh0, Ga);
            f32x4 Gb = mm(gh, bsl1, bgC); Gb = mm(gl, bsh1, Gb); Gb = mm(gh, bsh1, Gb);
            l00 = -redq(dot4(dh0, Ga));
            l10 = -redq(dot4(dh1, Gb));
        }
        {
            half4 gh = agh_s[1*64 + lane], gl = agl_s[1*64 + lane];
            f32x4 bgC = *(const f32x4*)(&bgt_s[1*16 + q*4]);
            f32x4 Ga = mm(gh, bsl0, bgC); Ga = mm(gl, bsh0, Ga); Ga = mm(gh, bsh0, Ga);
            f32x4 Gb = mm(gh, bsl1, bgC); Gb = mm(gl, bsh1, Gb); Gb = mm(gh, bsh1, Gb);
            l01 = -redq(dot4(dh0, Ga));
            l11 = -redq(dot4(dh1, Gb));
        }
        {
            half4 gh = agh_s[2*64 + lane], gl = agl_s[2*64 + lane];
            f32x4 bgC = *(const f32x4*)(&bgt_s[2*16 + q*4]);
            f32x4 Ga = mm(gh, bsl0, bgC); Ga = mm(gl, bsh0, Ga); Ga = mm(gh, bsh0, Ga);
            f32x4 Gb = mm(gh, bsl1, bgC); Gb = mm(gl, bsh1, Gb); Gb = mm(gh, bsh1, Gb);
            l02 = -redq(dot4(dh0, Ga));
            l12 = -redq(dot4(dh1, Gb));
        }
        {
            half4 gh = agh_s[3*64 + lane], gl = agl_s[3*64 + lane];
            f32x4 bgC = *(const f32x4*)(&bgt_s[3*16 + q*4]);
            f32x4 Ga = mm(gh, bsl0, bgC); Ga = mm(gl, bsh0, Ga); Ga = mm(gh, bsh0, Ga);
            f32x4 Gb = mm(gh, bsl1, bgC); Gb = mm(gl, bsh1, Gb); Gb = mm(gh, bsh1, Gb);
            l03 = -redq(dot4(dh0, Ga));
            l13 = -redq(dot4(dh1, Gb));
        }

        // ua rows >= 4 are zero, so quad-reduce == broadcast of rows 0-3
        float u00 = 2.f * redq(ua0.x);
        float u01 = 2.f * redq(ua0.y);
        float u02 = 2.f * redq(ua0.z);
        float u03 = 2.f * redq(ua0.w);
        float u10 = 2.f * redq(ua1.x);
        float u11 = 2.f * redq(ua1.y);
        float u12 = 2.f * redq(ua1.z);
        float u13 = 2.f * redq(ua1.w);

        float viol0 = l00*u00 + l01*u01 + l02*u02 + l03*u03 - right0;
        float lsq0  = l00*l00 + l01*l01 + l02*l02 + l03*l03;
        float lam0  = viol0 > 0.f ? viol0 / (lsq0 + 1e-8f) : 0.f;
        float viol1 = l10*u10 + l11*u11 + l12*u12 + l13*u13 - right1;
        float lsq1  = l10*l10 + l11*l11 + l12*l12 + l13*l13;
        float lam1  = viol1 > 0.f ? viol1 / (lsq1 + 1e-8f) : 0.f;

        if (q == 0) {                      // lanes 0-15 store their token
            f32x4 uo0;
            uo0.x = u00 - lam0*l00; uo0.y = u01 - lam0*l01;
            uo0.z = u02 - lam0*l02; uo0.w = u03 - lam0*l03;
            *(f32x4*)(out + (size_t)(t0*16 + n) * ADIM) = uo0;
            f32x4 uo1;
            uo1.x = u10 - lam1*l10; uo1.y = u11 - lam1*l11;
            uo1.z = u12 - lam1*l12; uo1.w = u13 - lam1*l13;
            *(f32x4*)(out + (size_t)((t0+1)*16 + n) * ADIM) = uo1;
        }

        sv0 = nsv0; sv1 = nsv1;
    }
}

extern "C" void kernel_launch(void* const* d_in, const int* in_sizes, int n_in,
                              void* d_out, int out_size, void* d_ws, size_t ws_size,
                              hipStream_t stream) {
    (void)in_sizes; (void)n_in; (void)d_ws; (void)ws_size; (void)out_size;
    const float* state = (const float*)d_in[0];
    const float* Wc1   = (const float*)d_in[1];
    const float* bc1   = (const float*)d_in[2];
    const float* Wc2   = (const float*)d_in[3];
    const float* bc2   = (const float*)d_in[4];
    const float* Wh1   = (const float*)d_in[5];
    const float* bh1   = (const float*)d_in[6];
    const float* wh2   = (const float*)d_in[7];
    const float* bh2   = (const float*)d_in[8];
    const float* Wf    = (const float*)d_in[9];
    const float* bf    = (const float*)d_in[10];
    const float* Wg    = (const float*)d_in[11];
    const float* bg    = (const float*)d_in[12];
    float* out = (float*)d_out;

    hipLaunchKernelGGL(cbf_qp_kernel, dim3(NBLK), dim3(256), 0, stream,
                       state, Wc1, bc1, Wc2, bc2, Wh1, bh1, wh2, bh2,
                       Wf, bf, Wg, bg, out);
}